// Round 15
// baseline (4116.830 us; speedup 1.0000x reference)
//
#include <hip/hip_runtime.h>
#include <hip/hip_cooperative_groups.h>

namespace cg = cooperative_groups;

#define NT 499    // T-1 sequential steps
#define NB 64     // batch (= wave size, lane = b)
#define NN 512    // region width
#define ND 100    // input dim
#define NO 10     // output dim
#define NWAVE 16  // waves per WG (1024 threads) -> 4 waves/SIMD
#define KW 32     // k-slice width per wave (16*32 = 512)
#define NWG 256

// workspace layout (floats)
#define XT_SZ   (NT * ND * NB)     // XT[t][d][b] = X[t+1][b][d]
#define RBUF_SZ (2 * NN * NB)
#define XT_OFF  0
#define RM_OFF  (XT_OFF + XT_SZ)
#define RP_OFF  (RM_OFF + RBUF_SZ)
#define RS_OFF  (RP_OFF + RBUF_SZ)
#define FLAG_OFF (RS_OFF + RBUF_SZ)   // [0]=root, [16*(i+1)]=leaf i (i<16)
#define WPK_OFF  (FLAG_OFF + 8192)    // packed f16 weights (u32 k-pairs)
#define RPK_STRIDE ((NN / 2) * NB)    // u32 per packed r buffer
#define WMAT (NN * (NN / 2))          // 131072 u32 per packed 512x512 matrix

// sc write-through store: publishes r to the coherence point (R2-R14 proven).
__device__ __forceinline__ void st_cg_u(unsigned* p, unsigned v) {
  __hip_atomic_store(p, v, __ATOMIC_RELAXED, __HIP_MEMORY_SCOPE_AGENT);
}

// LLC-direct coherent load, SGPR-base + imm-offset form (R10-proven).
#define LD1(dst, base, voff, IMM) \
  asm volatile("global_load_dword %0, %1, %2 offset:" IMM " sc0 sc1" \
               : "=v"(dst) : "v"(voff), "s"(base))
#define LDR(u, base, voff) do { \
  LD1(u[0],  base, voff, "0");    LD1(u[1],  base, voff, "256");  \
  LD1(u[2],  base, voff, "512");  LD1(u[3],  base, voff, "768");  \
  LD1(u[4],  base, voff, "1024"); LD1(u[5],  base, voff, "1280"); \
  LD1(u[6],  base, voff, "1536"); LD1(u[7],  base, voff, "1792"); \
  LD1(u[8],  base, voff, "2048"); LD1(u[9],  base, voff, "2304"); \
  LD1(u[10], base, voff, "2560"); LD1(u[11], base, voff, "2816"); \
  LD1(u[12], base, voff, "3072"); LD1(u[13], base, voff, "3328"); \
  LD1(u[14], base, voff, "3584"); LD1(u[15], base, voff, "3840"); \
} while (0)

// legacy full-address LLC-direct load (epilogue only)
#define LD_SC(dst, addr) \
  asm volatile("global_load_dword %0, %1, off sc0 sc1" : "=v"(dst) : "v"(addr))

// f16-pair dot product with f32 accumulate (R12-proven).
#define DOT2(acc, a, w) \
  asm("v_dot2_f32_f16 %0, %1, %2, %0" : "+v"(acc) : "v"(a), "s"(w))

// f32 pair -> packed f16x2 (RTE via _Float16 cast)
__device__ __forceinline__ unsigned f2h2(float a, float b) {
  union { _Float16 h[2]; unsigned u; } cv;
  cv.h[0] = (_Float16)a; cv.h[1] = (_Float16)b;
  return cv.u;
}

// Transpose X[t+1][b][d] -> XT[t][d][b] so the main loop's lane=b loads coalesce.
__global__ void xpose_kernel(const float* __restrict__ X, float* __restrict__ XT) {
  __shared__ float tile[NB * ND];
  const int t = blockIdx.x;
  const float* src = X + (size_t)(t + 1) * NB * ND;
  for (int i = threadIdx.x; i < NB * ND; i += blockDim.x) tile[i] = src[i];
  __syncthreads();
  float* dst = XT + (size_t)t * ND * NB;
  for (int i = threadIdx.x; i < NB * ND; i += blockDim.x) {
    const int d = i >> 6, b = i & 63;
    dst[i] = tile[b * ND + d];
  }
}

// Pack 6 recurrent matrices + W_out into f16 k-pairs (R12-proven).
__global__ void wpack_kernel(const float* __restrict__ W_rec_m1,
                             const float* __restrict__ W_m1_pmd,
                             const float* __restrict__ W_pmd_m1,
                             const float* __restrict__ W_rec_pmd,
                             const float* __restrict__ W_s1_m1,
                             const float* __restrict__ W_rec_s1,
                             const float* __restrict__ W_out,
                             unsigned* __restrict__ WPK) {
  const int idx = blockIdx.x, t = threadIdx.x;   // t = k2 in [0,256)
  const float* src; unsigned* dst;
  if (idx < 6 * NN) {
    const int mat = idx >> 9, row = idx & (NN - 1);
    const float* m[6] = {W_rec_m1, W_m1_pmd, W_pmd_m1, W_rec_pmd, W_s1_m1, W_rec_s1};
    src = m[mat] + (size_t)row * NN;
    dst = WPK + (size_t)mat * WMAT + (size_t)row * (NN / 2);
  } else {
    const int row = idx - 6 * NN;                // W_out rows 0..9
    src = W_out + (size_t)row * NN;
    dst = WPK + (size_t)6 * WMAT + (size_t)row * (NN / 2);
  }
  union { _Float16 h[2]; unsigned u; } cv;
  cv.h[0] = (_Float16)src[2 * t];
  cv.h[1] = (_Float16)src[2 * t + 1];
  dst[t] = cv.u;
}

// Persistent cooperative kernel: 256 WGs x 1024 threads (16 waves = 4/SIMD).
// R15 = EXACT R12 structure (3 barriers, parallel publish, 16-arrive tree —
// R13/R14 proved the arrangement is a local optimum) + three latency
// micro-cuts that leave the structure untouched:
//  (1) counted vmcnt staging: um-burn at vmcnt(32), uP at vmcnt(16), uS at
//      vmcnt(0) — dot2 work overlaps the load tail (T4 principle);
//  (2) poller moved to wave15 lane0 (dlen=0 -> earliest-free wave);
//  (3) busy-spin poll (no s_sleep) for detection granularity.
__global__ void __launch_bounds__(1024, 4)
rnn_kernel(const float* __restrict__ XT,
           unsigned* __restrict__ rmPK, unsigned* __restrict__ rpPK,
           unsigned* __restrict__ rsPK,
           const unsigned* __restrict__ WPK,
           const float* __restrict__ b_m1, const float* __restrict__ b_pmd,
           const float* __restrict__ b_s1,
           const float* __restrict__ W_in_pmd, const float* __restrict__ W_in_s1,
           float* __restrict__ out,
           unsigned* __restrict__ flags)
{
  const int g    = blockIdx.x;
  const int grp  = g >> 4;                 // 16 groups of 16 WGs
  const int wave = __builtin_amdgcn_readfirstlane((int)threadIdx.x >> 6);
  const int lane = (int)threadIdx.x & 63;
  const int n0 = 2 * g, n1 = 2 * g + 1;
  const int m0 = __builtin_amdgcn_readfirstlane(wave * (KW / 2));  // packed idx
  const int d0 = __builtin_amdgcn_readfirstlane(wave * 7);
  int dlen = ND - d0; dlen = dlen < 0 ? 0 : (dlen > 7 ? 7 : dlen);
  const bool has_out = (g < NO);
  const unsigned voff = (unsigned)lane * 4u;   // shared per-lane byte offset

  __shared__ float red[NWAVE][7][64];   // 28 KB; slot 6 = window ao partials

  // ws is poisoned before every launch: zero packed r slot 0 + barrier words.
  for (int i = g * (int)blockDim.x + (int)threadIdx.x; i < RPK_STRIDE;
       i += (int)(gridDim.x * blockDim.x)) {
    rmPK[i] = 0u; rpPK[i] = 0u; rsPK[i] = 0u;
  }
  if (g <= 16 && threadIdx.x == 0) flags[g * 16] = 0u;   // root + 16 leaves

  // packed f16 weight row-slice pointers (wave-uniform -> s_load, K$-hot)
  const unsigned* wrm0b = WPK + (size_t)0 * WMAT + (size_t)n0 * (NN / 2) + m0;
  const unsigned* wrm1b = WPK + (size_t)0 * WMAT + (size_t)n1 * (NN / 2) + m0;
  const unsigned* wmp0b = WPK + (size_t)1 * WMAT + (size_t)n0 * (NN / 2) + m0;
  const unsigned* wmp1b = WPK + (size_t)1 * WMAT + (size_t)n1 * (NN / 2) + m0;
  const unsigned* wpm0b = WPK + (size_t)2 * WMAT + (size_t)n0 * (NN / 2) + m0;
  const unsigned* wpm1b = WPK + (size_t)2 * WMAT + (size_t)n1 * (NN / 2) + m0;
  const unsigned* wrp0b = WPK + (size_t)3 * WMAT + (size_t)n0 * (NN / 2) + m0;
  const unsigned* wrp1b = WPK + (size_t)3 * WMAT + (size_t)n1 * (NN / 2) + m0;
  const unsigned* wsm0b = WPK + (size_t)4 * WMAT + (size_t)n0 * (NN / 2) + m0;
  const unsigned* wsm1b = WPK + (size_t)4 * WMAT + (size_t)n1 * (NN / 2) + m0;
  const unsigned* wrs0b = WPK + (size_t)5 * WMAT + (size_t)n0 * (NN / 2) + m0;
  const unsigned* wrs1b = WPK + (size_t)5 * WMAT + (size_t)n1 * (NN / 2) + m0;
  const unsigned* wob   = WPK + (size_t)6 * WMAT
                              + (size_t)(has_out ? g : 0) * (NN / 2) + m0;
  // X-path weights stay f32 (bounds quant error to the recurrent part)
  const float* wip0 = W_in_pmd + (size_t)n0 * ND + d0;
  const float* wip1 = W_in_pmd + (size_t)n1 * ND + d0;
  const float* wis0 = W_in_s1 + (size_t)n0 * ND + d0;
  const float* wis1 = W_in_s1 + (size_t)n1 * ND + d0;

  // publish role: wave j<3 owns region j's column pair; wave 3 reduces out
  unsigned* pubPK = nullptr; float bP0 = 0.f, bP1 = 0.f;
  if (wave == 0)      { pubPK = rmPK; bP0 = b_m1[n0];  bP1 = b_m1[n1]; }
  else if (wave == 1) { pubPK = rpPK; bP0 = b_pmd[n0]; bP1 = b_pmd[n1]; }
  else if (wave == 2) { pubPK = rsPK; bP0 = b_s1[n0];  bP1 = b_s1[n1]; }
  float xP0 = 0.f, xP1 = 0.f;

  // X-part accumulators for the upcoming step (computed during barrier wait)
  float apX0 = 0.f, apX1 = 0.f, asX0 = 0.f, asX1 = 0.f;
  {
    const float* xt = XT + d0 * NB + lane;   // ti = 0
    for (int d = 0; d < dlen; ++d) {
      const float v = xt[d * NB];
      apX0 = fmaf(v, wip0[d], apX0);
      apX1 = fmaf(v, wip1[d], apX1);
      asX0 = fmaf(v, wis0[d], asX0);
      asX1 = fmaf(v, wis1[d], asX1);
    }
  }

  // one-time heavyweight sync to order init (incl. wpack results) grid-wide
  cg::this_grid().sync();

  for (int ti = 0; ti < NT; ++ti) {
    const int cur = ti & 1, nxt = cur ^ 1;
    const unsigned* bM = rmPK + cur * RPK_STRIDE + m0 * NB;   // wave-uniform
    const unsigned* bP = rpPK + cur * RPK_STRIDE + m0 * NB;
    const unsigned* bS = rsPK + cur * RPK_STRIDE + m0 * NB;

    // ---- 48 LLC-direct loads; COUNTED waits stage the burn so dot2 work
    // overlaps the load tail (um issued first -> ready at vmcnt(32)) ----
    unsigned um[16], uP[16], uS[16];
    LDR(um, bM, voff);
    LDR(uP, bP, voff);
    LDR(uS, bS, voff);

    float am0 = 0.f, am1 = 0.f;
    float ap0 = apX0, ap1 = apX1, as0 = asX0, as1 = asX1;

    asm volatile("s_waitcnt vmcnt(32)" ::: "memory");
    __builtin_amdgcn_sched_barrier(0);   // rule #18: pin burn after wait
    #pragma unroll
    for (int j = 0; j < 16; ++j) {
      DOT2(am0, um[j], wrm0b[j]);
      DOT2(am1, um[j], wrm1b[j]);
      DOT2(ap0, um[j], wmp0b[j]);
      DOT2(ap1, um[j], wmp1b[j]);
    }
    asm volatile("s_waitcnt vmcnt(16)" ::: "memory");
    __builtin_amdgcn_sched_barrier(0);
    #pragma unroll
    for (int j = 0; j < 16; ++j) {
      DOT2(am0, uP[j], wpm0b[j]);
      DOT2(am1, uP[j], wpm1b[j]);
      DOT2(ap0, uP[j], wrp0b[j]);
      DOT2(ap1, uP[j], wrp1b[j]);
    }
    asm volatile("s_waitcnt vmcnt(0)" ::: "memory");
    __builtin_amdgcn_sched_barrier(0);
    #pragma unroll
    for (int j = 0; j < 16; ++j) {
      DOT2(am0, uS[j], wsm0b[j]);
      DOT2(am1, uS[j], wsm1b[j]);
      DOT2(as0, uS[j], wrs0b[j]);
      DOT2(as1, uS[j], wrs1b[j]);
    }

    red[wave][0][lane] = am0; red[wave][1][lane] = am1;
    red[wave][2][lane] = ap0; red[wave][3][lane] = ap1;
    red[wave][4][lane] = as0; red[wave][5][lane] = as1;
    __syncthreads();   // barrier #1

    // publish: wave j<3 reduces its region pair -> leaky+tanh -> f16x2 pack
    // -> ONE sc store. Wave 3 stores out[ti-2] from prior window's red[.][6].
    if (wave < 3) {
      float s0 = red[0][2 * wave][lane], s1 = red[0][2 * wave + 1][lane];
      #pragma unroll
      for (int w = 1; w < NWAVE; ++w) {
        s0 += red[w][2 * wave][lane];
        s1 += red[w][2 * wave + 1][lane];
      }
      xP0 = 0.9f * xP0 + 0.1f * (s0 + bP0);
      xP1 = 0.9f * xP1 + 0.1f * (s1 + bP1);
      st_cg_u(pubPK + nxt * RPK_STRIDE + g * NB + lane,
              f2h2(tanhf(xP0), tanhf(xP1)));
    } else if (wave == 3 && has_out && ti >= 2) {
      float s = red[0][6][lane];
      #pragma unroll
      for (int w = 1; w < NWAVE; ++w) s += red[w][6][lane];
      out[(size_t)(ti - 2) * (NB * NO) + lane * NO + g] = s;
    }

    // ---- barrier #2 drains the sc r-stores; thread0 arrives (R12 tree) ----
    __syncthreads();
    const unsigned tgtc = (unsigned)(ti + 1) * 16u;
    if (threadIdx.x == 0) {
      const unsigned old = __hip_atomic_fetch_add(
          &flags[(grp + 1) * 16], 1u, __ATOMIC_RELAXED, __HIP_MEMORY_SCOPE_AGENT);
      if (old == tgtc - 1u) {
        __hip_atomic_fetch_add(&flags[0], 1u, __ATOMIC_RELAXED,
                               __HIP_MEMORY_SCOPE_AGENT);
      }
    }

    // ---- barrier-wait window ----
    apX0 = 0.f; apX1 = 0.f; asX0 = 0.f; asX1 = 0.f;
    if (ti + 1 < NT) {
      const float* xt = XT + (size_t)(ti + 1) * ND * NB + d0 * NB + lane;
      for (int d = 0; d < dlen; ++d) {
        const float v = xt[d * NB];
        apX0 = fmaf(v, wip0[d], apX0);
        apX1 = fmaf(v, wip1[d], apX1);
        asX0 = fmaf(v, wis0[d], asX0);
        asX1 = fmaf(v, wis1[d], asX1);
      }
    }
    if (has_out) {
      float ao = 0.f;
      #pragma unroll
      for (int j = 0; j < 16; ++j) DOT2(ao, um[j], wob[j]);
      red[wave][6][lane] = ao;
    }

    // poller = wave15 lane0: dlen==0 (no X-window) -> reaches the poll
    // earliest; busy-spin (sc-load round trip is the natural backoff).
    if (threadIdx.x == 15 * 64) {
      while (__hip_atomic_load(&flags[0], __ATOMIC_RELAXED,
                               __HIP_MEMORY_SCOPE_AGENT) < tgtc)
        ;
      // no acquire fence: r reads are LLC-direct (R9-proven)
    }
    __syncthreads();   // barrier #3: wake
  }

  // epilogue (per-WG; has_out uniform within WG so barriers are safe):
  if (has_out) {
    if (wave == 3) {
      float s = red[0][6][lane];
      #pragma unroll
      for (int w = 1; w < NWAVE; ++w) s += red[w][6][lane];
      out[(size_t)(NT - 2) * (NB * NO) + lane * NO + g] = s;
    }
    __syncthreads();
    const unsigned* rmP = rmPK + (NT & 1) * RPK_STRIDE + m0 * NB + lane;
    unsigned um[16];
    #pragma unroll
    for (int k2 = 0; k2 < 16; ++k2) LD_SC(um[k2], rmP + k2 * NB);
    asm volatile("s_waitcnt vmcnt(0)" ::: "memory");
    __builtin_amdgcn_sched_barrier(0);
    float ao = 0.f;
    #pragma unroll
    for (int j = 0; j < 16; ++j) DOT2(ao, um[j], wob[j]);
    red[wave][6][lane] = ao;
    __syncthreads();
    if (wave == 3) {
      float t = red[0][6][lane];
      #pragma unroll
      for (int w = 1; w < NWAVE; ++w) t += red[w][6][lane];
      out[(size_t)(NT - 1) * (NB * NO) + lane * NO + g] = t;
    }
  }
}

extern "C" void kernel_launch(void* const* d_in, const int* in_sizes, int n_in,
                              void* d_out, int out_size, void* d_ws, size_t ws_size,
                              hipStream_t stream) {
  (void)in_sizes; (void)n_in; (void)out_size; (void)ws_size;
  const float* X         = (const float*)d_in[0];
  const float* W_rec_m1  = (const float*)d_in[1];
  const float* W_rec_pmd = (const float*)d_in[2];
  const float* W_rec_s1  = (const float*)d_in[3];
  const float* b_m1      = (const float*)d_in[4];
  const float* b_pmd     = (const float*)d_in[5];
  const float* b_s1      = (const float*)d_in[6];
  const float* W_pmd_m1  = (const float*)d_in[7];
  const float* W_s1_m1   = (const float*)d_in[8];
  const float* W_m1_pmd  = (const float*)d_in[9];
  const float* W_in_pmd  = (const float*)d_in[10];
  const float* W_in_s1   = (const float*)d_in[11];
  const float* W_out     = (const float*)d_in[12];
  float* out = (float*)d_out;

  float* wsf = (float*)d_ws;
  const float* XT = wsf + XT_OFF;
  float* XTw   = wsf + XT_OFF;
  unsigned* rmPK = (unsigned*)(wsf + RM_OFF);
  unsigned* rpPK = (unsigned*)(wsf + RP_OFF);
  unsigned* rsPK = (unsigned*)(wsf + RS_OFF);
  unsigned* flags = (unsigned*)(wsf + FLAG_OFF);
  unsigned* WPK   = (unsigned*)(wsf + WPK_OFF);

  xpose_kernel<<<NT, 256, 0, stream>>>(X, XTw);
  wpack_kernel<<<6 * NN + NO, 256, 0, stream>>>(
      W_rec_m1, W_m1_pmd, W_pmd_m1, W_rec_pmd, W_s1_m1, W_rec_s1, W_out, WPK);

  const unsigned* WPKc = WPK;
  void* args[12];
  args[0]  = (void*)&XT;
  args[1]  = (void*)&rmPK;  args[2]  = (void*)&rpPK; args[3]  = (void*)&rsPK;
  args[4]  = (void*)&WPKc;
  args[5]  = (void*)&b_m1;  args[6]  = (void*)&b_pmd; args[7]  = (void*)&b_s1;
  args[8]  = (void*)&W_in_pmd; args[9] = (void*)&W_in_s1;
  args[10] = (void*)&out;
  args[11] = (void*)&flags;
  hipLaunchCooperativeKernel((const void*)rnn_kernel, dim3(NWG), dim3(1024), args, 0, stream);
}

// Round 16
// 3269.363 us; speedup vs baseline: 1.2592x; 1.2592x over previous
//
#include <hip/hip_runtime.h>
#include <hip/hip_cooperative_groups.h>

namespace cg = cooperative_groups;

#define NT 499    // T-1 sequential steps
#define NB 64     // batch (= wave size, lane = b)
#define NN 512    // region width
#define ND 100    // input dim
#define NO 10     // output dim
#define NWAVE 16  // waves per WG (1024 threads) -> 4 waves/SIMD
#define KW 32     // k-slice width per wave (16*32 = 512)
#define NWG 256

// workspace layout (floats)
#define XT_SZ   (NT * ND * NB)     // XT[t][d][b] = X[t+1][b][d]
#define RBUF_SZ (2 * NN * NB)
#define XT_OFF  0
#define RM_OFF  (XT_OFF + XT_SZ)
#define RP_OFF  (RM_OFF + RBUF_SZ)
#define RS_OFF  (RP_OFF + RBUF_SZ)
#define FLAG_OFF (RS_OFF + RBUF_SZ)   // [0]=root, [16*(i+1)]=leaf i (i<16)
#define WPK_OFF  (FLAG_OFF + 8192)    // packed f16 weights (u32 k-pairs)
#define RPK_STRIDE ((NN / 2) * NB)    // u32 per packed r buffer
#define WMAT (NN * (NN / 2))          // 131072 u32 per packed 512x512 matrix

// sc write-through store: publishes r to the coherence point (R2-R10 proven).
__device__ __forceinline__ void st_cg_u(unsigned* p, unsigned v) {
  __hip_atomic_store(p, v, __ATOMIC_RELAXED, __HIP_MEMORY_SCOPE_AGENT);
}

// LLC-direct coherent load, SGPR-base + imm-offset form (R10-proven).
#define LD1(dst, base, voff, IMM) \
  asm volatile("global_load_dword %0, %1, %2 offset:" IMM " sc0 sc1" \
               : "=v"(dst) : "v"(voff), "s"(base))
#define LDR(u, base, voff) do { \
  LD1(u[0],  base, voff, "0");    LD1(u[1],  base, voff, "256");  \
  LD1(u[2],  base, voff, "512");  LD1(u[3],  base, voff, "768");  \
  LD1(u[4],  base, voff, "1024"); LD1(u[5],  base, voff, "1280"); \
  LD1(u[6],  base, voff, "1536"); LD1(u[7],  base, voff, "1792"); \
  LD1(u[8],  base, voff, "2048"); LD1(u[9],  base, voff, "2304"); \
  LD1(u[10], base, voff, "2560"); LD1(u[11], base, voff, "2816"); \
  LD1(u[12], base, voff, "3072"); LD1(u[13], base, voff, "3328"); \
  LD1(u[14], base, voff, "3584"); LD1(u[15], base, voff, "3840"); \
} while (0)

// legacy full-address LLC-direct load (epilogue only)
#define LD_SC(dst, addr) \
  asm volatile("global_load_dword %0, %1, off sc0 sc1" : "=v"(dst) : "v"(addr))

// f16-pair dot product with f32 accumulate: acc += a.lo*w.lo + a.hi*w.hi.
#define DOT2(acc, a, w) \
  asm("v_dot2_f32_f16 %0, %1, %2, %0" : "+v"(acc) : "v"(a), "s"(w))

// f32 pair -> packed f16x2 (RTE via _Float16 cast)
__device__ __forceinline__ unsigned f2h2(float a, float b) {
  union { _Float16 h[2]; unsigned u; } cv;
  cv.h[0] = (_Float16)a; cv.h[1] = (_Float16)b;
  return cv.u;
}

// Transpose X[t+1][b][d] -> XT[t][d][b] so the main loop's lane=b loads coalesce.
__global__ void xpose_kernel(const float* __restrict__ X, float* __restrict__ XT) {
  __shared__ float tile[NB * ND];
  const int t = blockIdx.x;
  const float* src = X + (size_t)(t + 1) * NB * ND;
  for (int i = threadIdx.x; i < NB * ND; i += blockDim.x) tile[i] = src[i];
  __syncthreads();
  float* dst = XT + (size_t)t * ND * NB;
  for (int i = threadIdx.x; i < NB * ND; i += blockDim.x) {
    const int d = i >> 6, b = i & 63;
    dst[i] = tile[b * ND + d];
  }
}

// Pack 6 recurrent matrices + W_out into f16 k-pairs: wpk[row][k2] =
// f16(W[row][2k2]) | f16(W[row][2k2+1])<<16. One block per row.
__global__ void wpack_kernel(const float* __restrict__ W_rec_m1,
                             const float* __restrict__ W_m1_pmd,
                             const float* __restrict__ W_pmd_m1,
                             const float* __restrict__ W_rec_pmd,
                             const float* __restrict__ W_s1_m1,
                             const float* __restrict__ W_rec_s1,
                             const float* __restrict__ W_out,
                             unsigned* __restrict__ WPK) {
  const int idx = blockIdx.x, t = threadIdx.x;   // t = k2 in [0,256)
  const float* src; unsigned* dst;
  if (idx < 6 * NN) {
    const int mat = idx >> 9, row = idx & (NN - 1);
    const float* m[6] = {W_rec_m1, W_m1_pmd, W_pmd_m1, W_rec_pmd, W_s1_m1, W_rec_s1};
    src = m[mat] + (size_t)row * NN;
    dst = WPK + (size_t)mat * WMAT + (size_t)row * (NN / 2);
  } else {
    const int row = idx - 6 * NN;                // W_out rows 0..9
    src = W_out + (size_t)row * NN;
    dst = WPK + (size_t)6 * WMAT + (size_t)row * (NN / 2);
  }
  union { _Float16 h[2]; unsigned u; } cv;
  cv.h[0] = (_Float16)src[2 * t];
  cv.h[1] = (_Float16)src[2 * t + 1];
  dst[t] = cv.u;
}

// Persistent cooperative kernel: 256 WGs x 1024 threads (16 waves = 4/SIMD).
// R16 = EXACT R12 revert (best verified: 3263 us). R13 (serial publish),
// R14 (triple-arrive), R15 (staged vmcnt + busy-spin) all regressed — R12's
// arrangement {parallel 3-wave publish, 3 barriers, 16-arrive tree with
// s_sleep poll, single vmcnt(0), LLC-direct sc loads, f16 dot2} is the
// empirical optimum of this structure family.
__global__ void __launch_bounds__(1024, 4)
rnn_kernel(const float* __restrict__ XT,
           unsigned* __restrict__ rmPK, unsigned* __restrict__ rpPK,
           unsigned* __restrict__ rsPK,
           const unsigned* __restrict__ WPK,
           const float* __restrict__ b_m1, const float* __restrict__ b_pmd,
           const float* __restrict__ b_s1,
           const float* __restrict__ W_in_pmd, const float* __restrict__ W_in_s1,
           float* __restrict__ out,
           unsigned* __restrict__ flags)
{
  const int g    = blockIdx.x;
  const int grp  = g >> 4;                 // 16 groups of 16 WGs
  const int wave = __builtin_amdgcn_readfirstlane((int)threadIdx.x >> 6);
  const int lane = (int)threadIdx.x & 63;
  const int n0 = 2 * g, n1 = 2 * g + 1;
  const int m0 = __builtin_amdgcn_readfirstlane(wave * (KW / 2));  // packed idx
  const int d0 = __builtin_amdgcn_readfirstlane(wave * 7);
  int dlen = ND - d0; dlen = dlen < 0 ? 0 : (dlen > 7 ? 7 : dlen);
  const bool has_out = (g < NO);
  const unsigned voff = (unsigned)lane * 4u;   // shared per-lane byte offset

  __shared__ float red[NWAVE][7][64];   // 28 KB; slot 6 = window ao partials

  // ws is poisoned before every launch: zero packed r slot 0 + barrier words.
  for (int i = g * (int)blockDim.x + (int)threadIdx.x; i < RPK_STRIDE;
       i += (int)(gridDim.x * blockDim.x)) {
    rmPK[i] = 0u; rpPK[i] = 0u; rsPK[i] = 0u;
  }
  if (g <= 16 && threadIdx.x == 0) flags[g * 16] = 0u;   // root + 16 leaves

  // packed f16 weight row-slice pointers (wave-uniform -> s_load, K$-hot)
  const unsigned* wrm0b = WPK + (size_t)0 * WMAT + (size_t)n0 * (NN / 2) + m0;
  const unsigned* wrm1b = WPK + (size_t)0 * WMAT + (size_t)n1 * (NN / 2) + m0;
  const unsigned* wmp0b = WPK + (size_t)1 * WMAT + (size_t)n0 * (NN / 2) + m0;
  const unsigned* wmp1b = WPK + (size_t)1 * WMAT + (size_t)n1 * (NN / 2) + m0;
  const unsigned* wpm0b = WPK + (size_t)2 * WMAT + (size_t)n0 * (NN / 2) + m0;
  const unsigned* wpm1b = WPK + (size_t)2 * WMAT + (size_t)n1 * (NN / 2) + m0;
  const unsigned* wrp0b = WPK + (size_t)3 * WMAT + (size_t)n0 * (NN / 2) + m0;
  const unsigned* wrp1b = WPK + (size_t)3 * WMAT + (size_t)n1 * (NN / 2) + m0;
  const unsigned* wsm0b = WPK + (size_t)4 * WMAT + (size_t)n0 * (NN / 2) + m0;
  const unsigned* wsm1b = WPK + (size_t)4 * WMAT + (size_t)n1 * (NN / 2) + m0;
  const unsigned* wrs0b = WPK + (size_t)5 * WMAT + (size_t)n0 * (NN / 2) + m0;
  const unsigned* wrs1b = WPK + (size_t)5 * WMAT + (size_t)n1 * (NN / 2) + m0;
  const unsigned* wob   = WPK + (size_t)6 * WMAT
                              + (size_t)(has_out ? g : 0) * (NN / 2) + m0;
  // X-path weights stay f32 (bounds quant error to the recurrent part)
  const float* wip0 = W_in_pmd + (size_t)n0 * ND + d0;
  const float* wip1 = W_in_pmd + (size_t)n1 * ND + d0;
  const float* wis0 = W_in_s1 + (size_t)n0 * ND + d0;
  const float* wis1 = W_in_s1 + (size_t)n1 * ND + d0;

  // publish role: wave j<3 owns region j's column pair; wave 3 reduces out
  unsigned* pubPK = nullptr; float bP0 = 0.f, bP1 = 0.f;
  if (wave == 0)      { pubPK = rmPK; bP0 = b_m1[n0];  bP1 = b_m1[n1]; }
  else if (wave == 1) { pubPK = rpPK; bP0 = b_pmd[n0]; bP1 = b_pmd[n1]; }
  else if (wave == 2) { pubPK = rsPK; bP0 = b_s1[n0];  bP1 = b_s1[n1]; }
  float xP0 = 0.f, xP1 = 0.f;

  // X-part accumulators for the upcoming step (computed during barrier wait)
  float apX0 = 0.f, apX1 = 0.f, asX0 = 0.f, asX1 = 0.f;
  {
    const float* xt = XT + d0 * NB + lane;   // ti = 0
    for (int d = 0; d < dlen; ++d) {
      const float v = xt[d * NB];
      apX0 = fmaf(v, wip0[d], apX0);
      apX1 = fmaf(v, wip1[d], apX1);
      asX0 = fmaf(v, wis0[d], asX0);
      asX1 = fmaf(v, wis1[d], asX1);
    }
  }

  // one-time heavyweight sync to order init (incl. wpack results) grid-wide
  cg::this_grid().sync();

  for (int ti = 0; ti < NT; ++ti) {
    const int cur = ti & 1, nxt = cur ^ 1;
    const unsigned* bM = rmPK + cur * RPK_STRIDE + m0 * NB;   // wave-uniform
    const unsigned* bP = rpPK + cur * RPK_STRIDE + m0 * NB;
    const unsigned* bS = rsPK + cur * RPK_STRIDE + m0 * NB;

    // ---- 48 LLC-direct loads, SGPR base + imm offsets, ONE vmcnt(0) ----
    unsigned um[16], uP[16], uS[16];
    LDR(um, bM, voff);
    LDR(uP, bP, voff);
    LDR(uS, bS, voff);
    asm volatile("s_waitcnt vmcnt(0)" ::: "memory");
    __builtin_amdgcn_sched_barrier(0);   // rule #18

    float am0 = 0.f, am1 = 0.f;
    float ap0 = apX0, ap1 = apX1, as0 = asX0, as1 = asX1;

    // dot2 burn: 192 instrs, zero unpack (um/uP/uS consumed packed)
    #pragma unroll
    for (int j = 0; j < 16; ++j) {
      DOT2(am0, um[j], wrm0b[j]);
      DOT2(am1, um[j], wrm1b[j]);
      DOT2(ap0, um[j], wmp0b[j]);
      DOT2(ap1, um[j], wmp1b[j]);
    }
    #pragma unroll
    for (int j = 0; j < 16; ++j) {
      DOT2(am0, uP[j], wpm0b[j]);
      DOT2(am1, uP[j], wpm1b[j]);
      DOT2(ap0, uP[j], wrp0b[j]);
      DOT2(ap1, uP[j], wrp1b[j]);
    }
    #pragma unroll
    for (int j = 0; j < 16; ++j) {
      DOT2(am0, uS[j], wsm0b[j]);
      DOT2(am1, uS[j], wsm1b[j]);
      DOT2(as0, uS[j], wrs0b[j]);
      DOT2(as1, uS[j], wrs1b[j]);
    }

    red[wave][0][lane] = am0; red[wave][1][lane] = am1;
    red[wave][2][lane] = ap0; red[wave][3][lane] = ap1;
    red[wave][4][lane] = as0; red[wave][5][lane] = as1;
    __syncthreads();

    // publish: wave j<3 reduces its region pair -> leaky+tanh -> f16x2 pack
    // -> ONE sc store. Wave 3 stores out[ti-2] from prior window's red[.][6].
    if (wave < 3) {
      float s0 = red[0][2 * wave][lane], s1 = red[0][2 * wave + 1][lane];
      #pragma unroll
      for (int w = 1; w < NWAVE; ++w) {
        s0 += red[w][2 * wave][lane];
        s1 += red[w][2 * wave + 1][lane];
      }
      xP0 = 0.9f * xP0 + 0.1f * (s0 + bP0);
      xP1 = 0.9f * xP1 + 0.1f * (s1 + bP1);
      st_cg_u(pubPK + nxt * RPK_STRIDE + g * NB + lane,
              f2h2(tanhf(xP0), tanhf(xP1)));
    } else if (wave == 3 && has_out && ti >= 2) {
      float s = red[0][6][lane];
      #pragma unroll
      for (int w = 1; w < NWAVE; ++w) s += red[w][6][lane];
      out[(size_t)(ti - 2) * (NB * NO) + lane * NO + g] = s;
    }

    // ---- two-level barrier tree (R10-proven) ----
    __syncthreads();
    const unsigned tgtc = (unsigned)(ti + 1) * 16u;
    if (threadIdx.x == 0) {
      const unsigned old = __hip_atomic_fetch_add(
          &flags[(grp + 1) * 16], 1u, __ATOMIC_RELAXED, __HIP_MEMORY_SCOPE_AGENT);
      if (old == tgtc - 1u) {
        __hip_atomic_fetch_add(&flags[0], 1u, __ATOMIC_RELAXED,
                               __HIP_MEMORY_SCOPE_AGENT);
      }
    }

    // ---- barrier-wait window ----
    apX0 = 0.f; apX1 = 0.f; asX0 = 0.f; asX1 = 0.f;
    if (ti + 1 < NT) {
      const float* xt = XT + (size_t)(ti + 1) * ND * NB + d0 * NB + lane;
      for (int d = 0; d < dlen; ++d) {
        const float v = xt[d * NB];
        apX0 = fmaf(v, wip0[d], apX0);
        apX1 = fmaf(v, wip1[d], apX1);
        asX0 = fmaf(v, wis0[d], asX0);
        asX1 = fmaf(v, wis1[d], asX1);
      }
    }
    if (has_out) {
      float ao = 0.f;
      #pragma unroll
      for (int j = 0; j < 16; ++j) DOT2(ao, um[j], wob[j]);
      red[wave][6][lane] = ao;
    }

    if (threadIdx.x == 0) {
      while (__hip_atomic_load(&flags[0], __ATOMIC_RELAXED,
                               __HIP_MEMORY_SCOPE_AGENT) < tgtc)
        __builtin_amdgcn_s_sleep(1);
      // no acquire fence: r reads are LLC-direct (R9-proven)
    }
    __syncthreads();
  }

  // epilogue (per-WG; has_out uniform within WG so barriers are safe):
  if (has_out) {
    if (wave == 3) {
      float s = red[0][6][lane];
      #pragma unroll
      for (int w = 1; w < NWAVE; ++w) s += red[w][6][lane];
      out[(size_t)(NT - 2) * (NB * NO) + lane * NO + g] = s;
    }
    __syncthreads();
    const unsigned* rmP = rmPK + (NT & 1) * RPK_STRIDE + m0 * NB + lane;
    unsigned um[16];
    #pragma unroll
    for (int k2 = 0; k2 < 16; ++k2) LD_SC(um[k2], rmP + k2 * NB);
    asm volatile("s_waitcnt vmcnt(0)" ::: "memory");
    __builtin_amdgcn_sched_barrier(0);
    float ao = 0.f;
    #pragma unroll
    for (int j = 0; j < 16; ++j) DOT2(ao, um[j], wob[j]);
    red[wave][6][lane] = ao;
    __syncthreads();
    if (wave == 3) {
      float t = red[0][6][lane];
      #pragma unroll
      for (int w = 1; w < NWAVE; ++w) t += red[w][6][lane];
      out[(size_t)(NT - 1) * (NB * NO) + lane * NO + g] = t;
    }
  }
}

extern "C" void kernel_launch(void* const* d_in, const int* in_sizes, int n_in,
                              void* d_out, int out_size, void* d_ws, size_t ws_size,
                              hipStream_t stream) {
  (void)in_sizes; (void)n_in; (void)out_size; (void)ws_size;
  const float* X         = (const float*)d_in[0];
  const float* W_rec_m1  = (const float*)d_in[1];
  const float* W_rec_pmd = (const float*)d_in[2];
  const float* W_rec_s1  = (const float*)d_in[3];
  const float* b_m1      = (const float*)d_in[4];
  const float* b_pmd     = (const float*)d_in[5];
  const float* b_s1      = (const float*)d_in[6];
  const float* W_pmd_m1  = (const float*)d_in[7];
  const float* W_s1_m1   = (const float*)d_in[8];
  const float* W_m1_pmd  = (const float*)d_in[9];
  const float* W_in_pmd  = (const float*)d_in[10];
  const float* W_in_s1   = (const float*)d_in[11];
  const float* W_out     = (const float*)d_in[12];
  float* out = (float*)d_out;

  float* wsf = (float*)d_ws;
  const float* XT = wsf + XT_OFF;
  float* XTw   = wsf + XT_OFF;
  unsigned* rmPK = (unsigned*)(wsf + RM_OFF);
  unsigned* rpPK = (unsigned*)(wsf + RP_OFF);
  unsigned* rsPK = (unsigned*)(wsf + RS_OFF);
  unsigned* flags = (unsigned*)(wsf + FLAG_OFF);
  unsigned* WPK   = (unsigned*)(wsf + WPK_OFF);

  xpose_kernel<<<NT, 256, 0, stream>>>(X, XTw);
  wpack_kernel<<<6 * NN + NO, 256, 0, stream>>>(
      W_rec_m1, W_m1_pmd, W_pmd_m1, W_rec_pmd, W_s1_m1, W_rec_s1, W_out, WPK);

  const unsigned* WPKc = WPK;
  void* args[12];
  args[0]  = (void*)&XT;
  args[1]  = (void*)&rmPK;  args[2]  = (void*)&rpPK; args[3]  = (void*)&rsPK;
  args[4]  = (void*)&WPKc;
  args[5]  = (void*)&b_m1;  args[6]  = (void*)&b_pmd; args[7]  = (void*)&b_s1;
  args[8]  = (void*)&W_in_pmd; args[9] = (void*)&W_in_s1;
  args[10] = (void*)&out;
  args[11] = (void*)&flags;
  hipLaunchCooperativeKernel((const void*)rnn_kernel, dim3(NWG), dim3(1024), args, 0, stream);
}